// Round 12
// baseline (458.388 us; speedup 1.0000x reference)
//
#include <hip/hip_runtime.h>
#include <hip/hip_bf16.h>

#define N_NODES 50000
#define N_EDGES 800000
#define F 256
#define NGRAPH 64
#define NCLS 16
#define NBLK_N 196   // ceil(50000/256)

typedef short short8 __attribute__((ext_vector_type(8)));
typedef float f32x4 __attribute__((ext_vector_type(4)));

__device__ __forceinline__ float bf2f(ushort u) {
    unsigned v = ((unsigned)u) << 16;
    return __uint_as_float(v);
}
__device__ __forceinline__ ushort f2bf(float f) {
    __hip_bfloat16 b = __float2bfloat16(f);   // RNE
    return *reinterpret_cast<ushort*>(&b);
}
__device__ __forceinline__ float bflo(uint u) { return __uint_as_float(u << 16); }
__device__ __forceinline__ float bfhi(uint u) { return __uint_as_float(u & 0xffff0000u); }

// ---------------- init (zeroed buffers, fused) ----------------

__global__ __launch_bounds__(256) void k_init(int* __restrict__ ecnt,
                                              float* __restrict__ pool,
                                              float* __restrict__ cnt) {
    int i = blockIdx.x * 256 + threadIdx.x;
    if (i < N_NODES) ecnt[i] = 0;
    if (i < NGRAPH * NCLS) pool[i] = 0.f;
    if (i < NGRAPH) cnt[i] = 0.f;
}

__global__ __launch_bounds__(256) void k_count(const int* __restrict__ dst,
                                               int* __restrict__ ecnt) {
    int e = blockIdx.x * 256 + threadIdx.x;
    if (e < N_EDGES) atomicAdd(&ecnt[dst[e]], 1);
}

// block-scan over ecnt; also emits dinv (fused)
__global__ __launch_bounds__(256) void k_scan_block(const int* __restrict__ ecnt,
                                                    int* __restrict__ rowptr,
                                                    int* __restrict__ blkSum,
                                                    float* __restrict__ dinv) {
    __shared__ int sh[256];
    int i = blockIdx.x * 256 + threadIdx.x;
    int v = (i < N_NODES) ? ecnt[i] : 0;
    sh[threadIdx.x] = v;
    __syncthreads();
#pragma unroll
    for (int off = 1; off < 256; off <<= 1) {
        int t = (threadIdx.x >= off) ? sh[threadIdx.x - off] : 0;
        __syncthreads();
        sh[threadIdx.x] += t;
        __syncthreads();
    }
    if (i < N_NODES) {
        rowptr[i] = sh[threadIdx.x] - v;
        dinv[i] = rsqrtf((float)(v + 1));   // +1 self-loop
    }
    if (threadIdx.x == 255) blkSum[blockIdx.x] = sh[255];
}

// per-block: reduce blkSum[0..bid) inline, add.
__global__ __launch_bounds__(256) void k_scan_add(const int* __restrict__ blkSum,
                                                  int* __restrict__ rowptr,
                                                  int* __restrict__ cursor) {
    __shared__ int sh[256];
    int t = threadIdx.x;
    sh[t] = (t < NBLK_N && t < (int)blockIdx.x) ? blkSum[t] : 0;
    __syncthreads();
#pragma unroll
    for (int off = 128; off > 0; off >>= 1) {
        if (t < off) sh[t] += sh[t + off];
        __syncthreads();
    }
    int base = sh[0];
    int i = blockIdx.x * 256 + t;
    if (i < N_NODES) {
        int r = rowptr[i] + base;
        rowptr[i] = r;
        cursor[i] = r;
    }
    if (i == 0) rowptr[N_NODES] = N_EDGES;
}

__global__ __launch_bounds__(256) void k_fill_csr(const int* __restrict__ src,
                                                  const int* __restrict__ dst,
                                                  int* __restrict__ cursor,
                                                  ushort* __restrict__ csr16) {
    int e = blockIdx.x * 256 + threadIdx.x;
    if (e >= N_EDGES) return;
    int s = src[e];
    int d = dst[e];
    int p = atomicAdd(&cursor[d], 1);
    csr16[p] = (ushort)s;
}

// ---------------- weight pack: all three 256x256 in one launch ----------------

__global__ __launch_bounds__(256) void k_wpack3(const float* __restrict__ W1,
                                                const float* __restrict__ W2,
                                                const float* __restrict__ W3,
                                                ushort* __restrict__ Wp) {
    int gid = blockIdx.x * 256 + threadIdx.x;
    int which = gid >> 13;          // 8192 frag-groups per matrix
    int idx = gid & 8191;
    const float* W = (which == 0) ? W1 : (which == 1) ? W2 : W3;
    ushort* o = Wp + (size_t)which * 65536;
    int lane = idx & 63;
    int ks = (idx >> 6) & 7;
    int ctg = idx >> 9;
    int kbase = ks * 32 + (lane >> 4) * 8;
    int col = ctg * 16 + (lane & 15);
    short8 v;
#pragma unroll
    for (int e = 0; e < 8; ++e)
        v[e] = (short)f2bf(W[(size_t)(kbase + e) * 256 + col]);
    *(short8*)(o + (size_t)idx * 8) = v;
}

// ---------------- MFMA GEMM, dinv-prescaled bf16 out ----------------
// 512 thr / 8 waves; BM=64; wave wv owns cols [wv*32, wv*32+32) (ct 2wv,2wv+1).
// wf[2][8]=64 VGPR resident, af[8]=32, acc 8 -> ~124 VGPR, no forced occupancy
// cap (spill-free). Full-block LDS C-stage per msub -> 512B-contiguous stores.

template <int F32IN>
__global__ __launch_bounds__(512) void k_mfma256(const void* __restrict__ Av,
                                                 const ushort* __restrict__ Wp,
                                                 const float* __restrict__ dinv,
                                                 ushort* __restrict__ C) {
    __shared__ __align__(16) ushort cs[16 * 264];   // 16 rows, 264-elem stride
    const int t = threadIdx.x;
    const int wv = t >> 6;         // 0..7
    const int l = t & 63;
    const int m0 = blockIdx.x * 64;
    const int lrow = l & 15;
    const int lk = (l >> 4) * 8;

    short8 wf[2][8];
    const short8* wp = (const short8*)Wp;
#pragma unroll
    for (int c2 = 0; c2 < 2; ++c2)
#pragma unroll
        for (int ks = 0; ks < 8; ++ks)
            wf[c2][ks] = wp[(size_t)(((2 * wv + c2) * 8 + ks) * 64) + l];

#pragma unroll
    for (int msub = 0; msub < 4; ++msub) {
        int arow = m0 + msub * 16 + lrow;
        if (arow >= N_NODES) arow = N_NODES - 1;
        short8 af[8];
        if (F32IN) {
            const float* ap = (const float*)Av + (size_t)arow * F + lk;
#pragma unroll
            for (int ks = 0; ks < 8; ++ks) {
                float4 a0 = *(const float4*)(ap + ks * 32);
                float4 a1 = *(const float4*)(ap + ks * 32 + 4);
                af[ks][0] = (short)f2bf(a0.x); af[ks][1] = (short)f2bf(a0.y);
                af[ks][2] = (short)f2bf(a0.z); af[ks][3] = (short)f2bf(a0.w);
                af[ks][4] = (short)f2bf(a1.x); af[ks][5] = (short)f2bf(a1.y);
                af[ks][6] = (short)f2bf(a1.z); af[ks][7] = (short)f2bf(a1.w);
            }
        } else {
            const ushort* ap = (const ushort*)Av + (size_t)arow * F + lk;
#pragma unroll
            for (int ks = 0; ks < 8; ++ks)
                af[ks] = *(const short8*)(ap + ks * 32);
        }

        f32x4 acc[2];
        acc[0] = (f32x4){0.f, 0.f, 0.f, 0.f};
        acc[1] = (f32x4){0.f, 0.f, 0.f, 0.f};
#pragma unroll
        for (int ks = 0; ks < 8; ++ks) {
            acc[0] = __builtin_amdgcn_mfma_f32_16x16x32_bf16(af[ks], wf[0][ks], acc[0], 0, 0, 0);
            acc[1] = __builtin_amdgcn_mfma_f32_16x16x32_bf16(af[ks], wf[1][ks], acc[1], 0, 0, 0);
        }

        int orow0 = msub * 16 + (l >> 4) * 4;   // row within tile
        float dv[4];
#pragma unroll
        for (int r = 0; r < 4; ++r) {
            int gr = m0 + orow0 + r;
            dv[r] = (gr < N_NODES) ? dinv[gr] : 0.f;
        }

        // stage whole 16x256 slab in LDS
#pragma unroll
        for (int c2 = 0; c2 < 2; ++c2) {
            int col = (2 * wv + c2) * 16 + (l & 15);
#pragma unroll
            for (int r = 0; r < 4; ++r) {
                int row = (l >> 4) * 4 + r;
                cs[row * 264 + col] = f2bf(acc[c2][r] * dv[r]);
            }
        }
        __syncthreads();
        // read back row-major: 512 thr x short8 = 16 rows x 256 cols
        {
            int row = t >> 5;            // 0..15
            int coff = (t & 31) * 8;     // 0..248
            short8 v = *(const short8*)&cs[row * 264 + coff];
            int orow = m0 + msub * 16 + row;
            if (orow < N_NODES)
                *(short8*)(C + (size_t)orow * F + coff) = v;
        }
        __syncthreads();
    }
}

// ---------------- fused gather aggregation, F=256, bf16 in/out ----------------
// 2-slot wave: 32 lanes x 16B cover one 512B row.
// H dinv-prescaled: out_d = act( bias + dinv_d * (sum_{s in N(d)} H[s] + H[d]) )
// MODE 1: relu(agg)   MODE 2: relu(relu(agg) + hc)

template <int MODE>
__global__ __launch_bounds__(256) void k_gather256(const ushort* __restrict__ H,
                                                   const float* __restrict__ bias,
                                                   const float* __restrict__ dinv,
                                                   const int* __restrict__ rowptr,
                                                   const ushort* __restrict__ csr16,
                                                   const ushort* __restrict__ hc,
                                                   ushort* __restrict__ OUT) {
    int gid = blockIdx.x * 256 + threadIdx.x;
    int n = gid >> 6;
    int lane = gid & 63;
    if (n >= N_NODES) return;
    const int slot = lane >> 5;    // 0..1
    const int c = (lane & 31) * 8; // this lane's 8-feat block

    float acc[8];
#pragma unroll
    for (int j = 0; j < 8; ++j) acc[j] = 0.f;

    int i = rowptr[n] + slot;
    const int end = rowptr[n + 1];
    for (; i + 6 < end; i += 8) {
        int s0 = csr16[i], s1 = csr16[i + 2], s2 = csr16[i + 4], s3 = csr16[i + 6];
        short8 v0 = *(const short8*)(H + (size_t)s0 * F + c);
        short8 v1 = *(const short8*)(H + (size_t)s1 * F + c);
        short8 v2 = *(const short8*)(H + (size_t)s2 * F + c);
        short8 v3 = *(const short8*)(H + (size_t)s3 * F + c);
#pragma unroll
        for (int j = 0; j < 8; ++j)
            acc[j] += (bf2f((ushort)v0[j]) + bf2f((ushort)v1[j])) +
                      (bf2f((ushort)v2[j]) + bf2f((ushort)v3[j]));
    }
    for (; i < end; i += 2) {
        int s0 = csr16[i];
        short8 v0 = *(const short8*)(H + (size_t)s0 * F + c);
#pragma unroll
        for (int j = 0; j < 8; ++j) acc[j] += bf2f((ushort)v0[j]);
    }

#pragma unroll
    for (int j = 0; j < 8; ++j) acc[j] += __shfl_xor(acc[j], 32);

    if (slot == 0) {
        const short8 h = *(const short8*)(H + (size_t)n * F + c);
        const float4 b0 = *(const float4*)(bias + c);
        const float4 b1 = *(const float4*)(bias + c + 4);
        float bb[8] = {b0.x, b0.y, b0.z, b0.w, b1.x, b1.y, b1.z, b1.w};
        float di = dinv[n];
        float s[8];
#pragma unroll
        for (int j = 0; j < 8; ++j)
            s[j] = bb[j] + di * (acc[j] + bf2f((ushort)h[j]));

        short8 ov;
        if (MODE == 1) {
#pragma unroll
            for (int j = 0; j < 8; ++j)
                ov[j] = (short)f2bf(fmaxf(s[j], 0.f));
        } else {
            const short8 hv = *(const short8*)(hc + (size_t)n * F + c);
#pragma unroll
            for (int j = 0; j < 8; ++j)
                ov[j] = (short)f2bf(fmaxf(fmaxf(s[j], 0.f) + bf2f((ushort)hv[j]), 0.f));
        }
        *(short8*)(OUT + (size_t)n * F + c) = ov;
    }
}

// ---------------- layer 4: GEMM 256 -> 16, dinv-prescaled bf16 out ----------------

__global__ __launch_bounds__(256) void k_gemm16(const ushort* __restrict__ A,
                                                const float* __restrict__ W4,
                                                const float* __restrict__ dinv,
                                                ushort* __restrict__ C) {
    __shared__ float Ws[256][16];
    const int t = threadIdx.x;
    {
        const float4* wp = (const float4*)(W4 + (size_t)t * 16);
        float4 a = wp[0], b = wp[1], c = wp[2], d = wp[3];
        float4* sp = (float4*)&Ws[t][0];
        sp[0] = a; sp[1] = b; sp[2] = c; sp[3] = d;
    }
    __syncthreads();
    int row = blockIdx.x * 256 + t;
    if (row >= N_NODES) return;
    const short8* ap = (const short8*)(A + (size_t)row * F);
    float acc[16];
#pragma unroll
    for (int c = 0; c < 16; ++c) acc[c] = 0.f;
    for (int k8 = 0; k8 < 32; ++k8) {
        short8 a8 = ap[k8];
#pragma unroll
        for (int j = 0; j < 8; ++j) {
            float av = bf2f((ushort)a8[j]);
            const float4* wr = (const float4*)&Ws[k8 * 8 + j][0];
            float4 w0 = wr[0], w1 = wr[1], w2 = wr[2], w3 = wr[3];
            acc[0]  += av * w0.x; acc[1]  += av * w0.y;
            acc[2]  += av * w0.z; acc[3]  += av * w0.w;
            acc[4]  += av * w1.x; acc[5]  += av * w1.y;
            acc[6]  += av * w1.z; acc[7]  += av * w1.w;
            acc[8]  += av * w2.x; acc[9]  += av * w2.y;
            acc[10] += av * w2.z; acc[11] += av * w2.w;
            acc[12] += av * w3.x; acc[13] += av * w3.y;
            acc[14] += av * w3.z; acc[15] += av * w3.w;
        }
    }
    float dv = dinv[row];
    short8 o0, o1;
#pragma unroll
    for (int c = 0; c < 8; ++c) o0[c] = (short)f2bf(acc[c] * dv);
#pragma unroll
    for (int c = 0; c < 8; ++c) o1[c] = (short)f2bf(acc[8 + c] * dv);
    short8* op = (short8*)(C + (size_t)row * 16);
    op[0] = o0; op[1] = o1;
}

// ---------------- fused layer-4 gather + mean-pool accumulate ----------------

__global__ __launch_bounds__(256) void k_g16pool(const ushort* __restrict__ G16,
                                                 const float* __restrict__ bias,
                                                 const float* __restrict__ dinv,
                                                 const int* __restrict__ rowptr,
                                                 const ushort* __restrict__ csr16,
                                                 const int* __restrict__ batch,
                                                 float* __restrict__ pool,
                                                 float* __restrict__ cnt) {
    __shared__ float ps[NGRAPH][NCLS];
    __shared__ float pc[NGRAPH];
    for (int i = threadIdx.x; i < NGRAPH * NCLS; i += 256) ((float*)ps)[i] = 0.f;
    if (threadIdx.x < NGRAPH) pc[threadIdx.x] = 0.f;
    __syncthreads();

    int gid = blockIdx.x * 256 + threadIdx.x;
    int n = gid >> 2;
    int q = (gid & 3) * 4;
    if (n < N_NODES) {
        float ax = 0.f, ay = 0.f, az = 0.f, aw = 0.f;
        const int end = rowptr[n + 1];
        for (int i = rowptr[n]; i < end; ++i) {
            int s0 = csr16[i];
            const uint2 u = *(const uint2*)(G16 + (size_t)s0 * 16 + q);
            ax += bflo(u.x); ay += bfhi(u.x);
            az += bflo(u.y); aw += bfhi(u.y);
        }
        const uint2 hu = *(const uint2*)(G16 + (size_t)n * 16 + q);
        const float4 b = *(const float4*)(bias + q);
        float di = dinv[n];
        int g = batch[n];
        atomicAdd(&ps[g][q + 0], b.x + di * (ax + bflo(hu.x)));
        atomicAdd(&ps[g][q + 1], b.y + di * (ay + bfhi(hu.x)));
        atomicAdd(&ps[g][q + 2], b.z + di * (az + bflo(hu.y)));
        atomicAdd(&ps[g][q + 3], b.w + di * (aw + bfhi(hu.y)));
        if ((gid & 3) == 0) atomicAdd(&pc[g], 1.f);
    }
    __syncthreads();

    for (int i = threadIdx.x; i < NGRAPH * NCLS; i += 256) {
        float v = ((float*)ps)[i];
        if (v != 0.f) unsafeAtomicAdd(&pool[i], v);
    }
    if (threadIdx.x < NGRAPH) {
        float v = pc[threadIdx.x];
        if (v > 0.f) unsafeAtomicAdd(&cnt[threadIdx.x], v);
    }
}

__global__ __launch_bounds__(256) void k_final(const float* __restrict__ pool,
                                               const float* __restrict__ cnt,
                                               float* __restrict__ out) {
    int i = blockIdx.x * 256 + threadIdx.x;
    if (i < NGRAPH * NCLS) out[i] = pool[i] / fmaxf(cnt[i >> 4], 1.f);
}

// ---------------- host ----------------

extern "C" void kernel_launch(void* const* d_in, const int* in_sizes, int n_in,
                              void* d_out, int out_size, void* d_ws, size_t ws_size,
                              hipStream_t stream) {
    const float* x   = (const float*)d_in[0];
    const int*   ei  = (const int*)d_in[1];
    const int*   bvec= (const int*)d_in[2];
    const float* W1  = (const float*)d_in[3];
    const float* b1  = (const float*)d_in[4];
    const float* W2  = (const float*)d_in[5];
    const float* b2  = (const float*)d_in[6];
    const float* W3  = (const float*)d_in[7];
    const float* b3  = (const float*)d_in[8];
    const float* W4  = (const float*)d_in[9];
    const float* b4  = (const float*)d_in[10];
    float* out = (float*)d_out;

    const int* src = ei;
    const int* dst = ei + N_EDGES;

    const size_t NF = (size_t)N_NODES * F;            // 12.8M elems
    ushort* P   = (ushort*)d_ws;                       // NF bf16
    ushort* Q   = P + NF;                              // NF bf16
    ushort* Hg  = Q + NF;                              // NF bf16 (prescaled GEMM out)
    ushort* G16 = Hg + NF;                             // N*16 bf16 (prescaled)
    float*  aux = (float*)(G16 + (size_t)N_NODES * 16 + 64);
    int*    ecnt   = (int*)aux;                        // N
    float*  dinv   = aux + N_NODES;                    // N
    int*    rowptr = (int*)(aux + 2 * N_NODES);        // N+1 (+pad)
    int*    cursor = (int*)(aux + 3 * N_NODES + 64);   // N
    int*    blkSum = (int*)(aux + 4 * N_NODES + 64);   // 256
    ushort* csr16  = (ushort*)(blkSum + 256);          // E ushorts
    float*  pool   = (float*)(csr16 + N_EDGES);        // 1024
    float*  cnt    = pool + NGRAPH * NCLS;             // 64
    ushort* Wp     = (ushort*)(cnt + NGRAPH);          // 3 x 65536

    const int BN = NBLK_N;                        // 196
    const int BE = (N_EDGES + 255) / 256;         // 3125
    const int BM = (N_NODES + 63) / 64;           // 782 MFMA blocks (BM=64)
    const int BG = (N_NODES * 64 + 255) / 256;    // 12500 (wave/node)
    const int B4 = (N_NODES * 4 + 255) / 256;     // 782

    // ---- CSR build + dinv + zero-init
    k_init<<<BN, 256, 0, stream>>>(ecnt, pool, cnt);
    k_count<<<BE, 256, 0, stream>>>(dst, ecnt);
    k_scan_block<<<BN, 256, 0, stream>>>(ecnt, rowptr, blkSum, dinv);
    k_scan_add<<<BN, 256, 0, stream>>>(blkSum, rowptr, cursor);
    k_fill_csr<<<BE, 256, 0, stream>>>(src, dst, cursor, csr16);

    // ---- weight packs (single launch)
    k_wpack3<<<96, 256, 0, stream>>>(W1, W2, W3, Wp);

    // ---- layer 1 (cast fused into GEMM): Hg = dinv*(x@W1); P = relu(agg(Hg))
    k_mfma256<1><<<BM, 512, 0, stream>>>(x, Wp, dinv, Hg);
    k_gather256<1><<<BG, 256, 0, stream>>>(Hg, b1, dinv, rowptr, csr16, nullptr, P);

    // ---- layer 2: Hg = dinv*(P@W2); Q = relu(relu(agg(Hg)) + P)
    k_mfma256<0><<<BM, 512, 0, stream>>>(P, Wp + 65536, dinv, Hg);
    k_gather256<2><<<BG, 256, 0, stream>>>(Hg, b2, dinv, rowptr, csr16, P, Q);

    // ---- layer 3: Hg = dinv*(Q@W3); P = relu(relu(agg(Hg)) + Q)
    k_mfma256<0><<<BM, 512, 0, stream>>>(Q, Wp + 131072, dinv, Hg);
    k_gather256<2><<<BG, 256, 0, stream>>>(Hg, b3, dinv, rowptr, csr16, Q, P);

    // ---- layer 4: G16 = dinv*(P@W4); fused gather+pool
    k_gemm16<<<BN, 256, 0, stream>>>(P, W4, dinv, G16);
    k_g16pool<<<B4, 256, 0, stream>>>(G16, b4, dinv, rowptr, csr16, bvec, pool, cnt);

    // ---- finalize
    k_final<<<4, 256, 0, stream>>>(pool, cnt, out);
}

// Round 13
// 399.217 us; speedup vs baseline: 1.1482x; 1.1482x over previous
//
#include <hip/hip_runtime.h>
#include <hip/hip_bf16.h>

#define N_NODES 50000
#define N_EDGES 800000
#define F 256
#define NGRAPH 64
#define NCLS 16
#define NBLK_N 196   // ceil(50000/256)

typedef short short8 __attribute__((ext_vector_type(8)));
typedef float f32x4 __attribute__((ext_vector_type(4)));

__device__ __forceinline__ float bf2f(ushort u) {
    unsigned v = ((unsigned)u) << 16;
    return __uint_as_float(v);
}
__device__ __forceinline__ ushort f2bf(float f) {
    __hip_bfloat16 b = __float2bfloat16(f);   // RNE
    return *reinterpret_cast<ushort*>(&b);
}
__device__ __forceinline__ float bflo(uint u) { return __uint_as_float(u << 16); }
__device__ __forceinline__ float bfhi(uint u) { return __uint_as_float(u & 0xffff0000u); }

// ---------------- init (zeroed buffers, fused) ----------------

__global__ __launch_bounds__(256) void k_init(int* __restrict__ ecnt,
                                              float* __restrict__ pool,
                                              float* __restrict__ cnt) {
    int i = blockIdx.x * 256 + threadIdx.x;
    if (i < N_NODES) ecnt[i] = 0;
    if (i < NGRAPH * NCLS) pool[i] = 0.f;
    if (i < NGRAPH) cnt[i] = 0.f;
}

__global__ __launch_bounds__(256) void k_count(const int* __restrict__ dst,
                                               int* __restrict__ ecnt) {
    int e = blockIdx.x * 256 + threadIdx.x;
    if (e < N_EDGES) atomicAdd(&ecnt[dst[e]], 1);
}

// block-scan over ecnt; also emits dinv (fused)
__global__ __launch_bounds__(256) void k_scan_block(const int* __restrict__ ecnt,
                                                    int* __restrict__ rowptr,
                                                    int* __restrict__ blkSum,
                                                    float* __restrict__ dinv) {
    __shared__ int sh[256];
    int i = blockIdx.x * 256 + threadIdx.x;
    int v = (i < N_NODES) ? ecnt[i] : 0;
    sh[threadIdx.x] = v;
    __syncthreads();
#pragma unroll
    for (int off = 1; off < 256; off <<= 1) {
        int t = (threadIdx.x >= off) ? sh[threadIdx.x - off] : 0;
        __syncthreads();
        sh[threadIdx.x] += t;
        __syncthreads();
    }
    if (i < N_NODES) {
        rowptr[i] = sh[threadIdx.x] - v;
        dinv[i] = rsqrtf((float)(v + 1));   // +1 self-loop
    }
    if (threadIdx.x == 255) blkSum[blockIdx.x] = sh[255];
}

// per-block: reduce blkSum[0..bid) inline, add.
__global__ __launch_bounds__(256) void k_scan_add(const int* __restrict__ blkSum,
                                                  int* __restrict__ rowptr,
                                                  int* __restrict__ cursor) {
    __shared__ int sh[256];
    int t = threadIdx.x;
    sh[t] = (t < NBLK_N && t < (int)blockIdx.x) ? blkSum[t] : 0;
    __syncthreads();
#pragma unroll
    for (int off = 128; off > 0; off >>= 1) {
        if (t < off) sh[t] += sh[t + off];
        __syncthreads();
    }
    int base = sh[0];
    int i = blockIdx.x * 256 + t;
    if (i < N_NODES) {
        int r = rowptr[i] + base;
        rowptr[i] = r;
        cursor[i] = r;
    }
    if (i == 0) rowptr[N_NODES] = N_EDGES;
}

__global__ __launch_bounds__(256) void k_fill_csr(const int* __restrict__ src,
                                                  const int* __restrict__ dst,
                                                  int* __restrict__ cursor,
                                                  ushort* __restrict__ csr16) {
    int e = blockIdx.x * 256 + threadIdx.x;
    if (e >= N_EDGES) return;
    int s = src[e];
    int d = dst[e];
    int p = atomicAdd(&cursor[d], 1);
    csr16[p] = (ushort)s;
}

// ---------------- weight pack: all three 256x256 in one launch ----------------

__global__ __launch_bounds__(256) void k_wpack3(const float* __restrict__ W1,
                                                const float* __restrict__ W2,
                                                const float* __restrict__ W3,
                                                ushort* __restrict__ Wp) {
    int gid = blockIdx.x * 256 + threadIdx.x;
    int which = gid >> 13;          // 8192 frag-groups per matrix
    int idx = gid & 8191;
    const float* W = (which == 0) ? W1 : (which == 1) ? W2 : W3;
    ushort* o = Wp + (size_t)which * 65536;
    int lane = idx & 63;
    int ks = (idx >> 6) & 7;
    int ctg = idx >> 9;
    int kbase = ks * 32 + (lane >> 4) * 8;
    int col = ctg * 16 + (lane & 15);
    short8 v;
#pragma unroll
    for (int e = 0; e < 8; ++e)
        v[e] = (short)f2bf(W[(size_t)(kbase + e) * 256 + col]);
    *(short8*)(o + (size_t)idx * 8) = v;
}

// ---------------- MFMA GEMM, dinv-prescaled bf16 out ----------------
// R10 per-wave structure (wf[4][8], intra-wave LDS slice, no barrier, lb(256,2))
// with BM=32 (2 msubs) -> 1563 blocks (6.1/CU schedulable) and pad-72 LDS rows.

template <int F32IN>
__global__ __launch_bounds__(256, 2) void k_mfma256(const void* __restrict__ Av,
                                                    const ushort* __restrict__ Wp,
                                                    const float* __restrict__ dinv,
                                                    ushort* __restrict__ C) {
    __shared__ __align__(16) ushort cs[4][16 * 72];   // padded rows (bank-rotating)
    const int t = threadIdx.x;
    const int wv = t >> 6;
    const int l = t & 63;
    const int m0 = blockIdx.x * 32;
    const int colbase = wv * 64;
    const int lrow = l & 15;
    const int lk = (l >> 4) * 8;

    short8 wf[4][8];
    const short8* wp = (const short8*)Wp;
#pragma unroll
    for (int ct = 0; ct < 4; ++ct)
#pragma unroll
        for (int ks = 0; ks < 8; ++ks)
            wf[ct][ks] = wp[(size_t)(((wv * 4 + ct) * 8 + ks) * 64) + l];

#pragma unroll
    for (int msub = 0; msub < 2; ++msub) {
        int arow = m0 + msub * 16 + lrow;
        if (arow >= N_NODES) arow = N_NODES - 1;
        short8 af[8];
        if (F32IN) {
            const float* ap = (const float*)Av + (size_t)arow * F + lk;
#pragma unroll
            for (int ks = 0; ks < 8; ++ks) {
                float4 a0 = *(const float4*)(ap + ks * 32);
                float4 a1 = *(const float4*)(ap + ks * 32 + 4);
                af[ks][0] = (short)f2bf(a0.x); af[ks][1] = (short)f2bf(a0.y);
                af[ks][2] = (short)f2bf(a0.z); af[ks][3] = (short)f2bf(a0.w);
                af[ks][4] = (short)f2bf(a1.x); af[ks][5] = (short)f2bf(a1.y);
                af[ks][6] = (short)f2bf(a1.z); af[ks][7] = (short)f2bf(a1.w);
            }
        } else {
            const ushort* ap = (const ushort*)Av + (size_t)arow * F + lk;
#pragma unroll
            for (int ks = 0; ks < 8; ++ks)
                af[ks] = *(const short8*)(ap + ks * 32);
        }

        f32x4 acc[4];
#pragma unroll
        for (int ct = 0; ct < 4; ++ct) acc[ct] = (f32x4){0.f, 0.f, 0.f, 0.f};
#pragma unroll
        for (int ks = 0; ks < 8; ++ks)
#pragma unroll
            for (int ct = 0; ct < 4; ++ct)
                acc[ct] = __builtin_amdgcn_mfma_f32_16x16x32_bf16(af[ks], wf[ct][ks], acc[ct], 0, 0, 0);

        int orow0 = m0 + msub * 16 + (l >> 4) * 4;
        float dv[4];
#pragma unroll
        for (int r = 0; r < 4; ++r)
            dv[r] = (orow0 + r < N_NODES) ? dinv[orow0 + r] : 0.f;

        // stage to this wave's LDS slice (intra-wave exchange, no barrier)
#pragma unroll
        for (int ct = 0; ct < 4; ++ct) {
            int col = ct * 16 + (l & 15);
#pragma unroll
            for (int r = 0; r < 4; ++r) {
                int row = (l >> 4) * 4 + r;
                cs[wv][row * 72 + col] = f2bf(acc[ct][r] * dv[r]);
            }
        }
        // read back row-major, store 128B-contiguous
#pragma unroll
        for (int h = 0; h < 2; ++h) {
            int row = h * 8 + (l >> 3);
            int coff = (l & 7) * 8;
            short8 v = *(const short8*)&cs[wv][row * 72 + coff];
            int orow = m0 + msub * 16 + row;
            if (orow < N_NODES)
                *(short8*)(C + (size_t)orow * F + colbase + coff) = v;
        }
    }
}

// ---------------- fused gather aggregation, F=256, bf16 in/out ----------------
// 2-slot wave: 32 lanes x 16B cover one 512B row.
// H dinv-prescaled: out_d = act( bias + dinv_d * (sum_{s in N(d)} H[s] + H[d]) )
// MODE 1: relu(agg)   MODE 2: relu(relu(agg) + hc)

template <int MODE>
__global__ __launch_bounds__(256) void k_gather256(const ushort* __restrict__ H,
                                                   const float* __restrict__ bias,
                                                   const float* __restrict__ dinv,
                                                   const int* __restrict__ rowptr,
                                                   const ushort* __restrict__ csr16,
                                                   const ushort* __restrict__ hc,
                                                   ushort* __restrict__ OUT) {
    int gid = blockIdx.x * 256 + threadIdx.x;
    int n = gid >> 6;
    int lane = gid & 63;
    if (n >= N_NODES) return;
    const int slot = lane >> 5;    // 0..1
    const int c = (lane & 31) * 8; // this lane's 8-feat block

    float acc[8];
#pragma unroll
    for (int j = 0; j < 8; ++j) acc[j] = 0.f;

    int i = rowptr[n] + slot;
    const int end = rowptr[n + 1];
    for (; i + 6 < end; i += 8) {
        int s0 = csr16[i], s1 = csr16[i + 2], s2 = csr16[i + 4], s3 = csr16[i + 6];
        short8 v0 = *(const short8*)(H + (size_t)s0 * F + c);
        short8 v1 = *(const short8*)(H + (size_t)s1 * F + c);
        short8 v2 = *(const short8*)(H + (size_t)s2 * F + c);
        short8 v3 = *(const short8*)(H + (size_t)s3 * F + c);
#pragma unroll
        for (int j = 0; j < 8; ++j)
            acc[j] += (bf2f((ushort)v0[j]) + bf2f((ushort)v1[j])) +
                      (bf2f((ushort)v2[j]) + bf2f((ushort)v3[j]));
    }
    for (; i < end; i += 2) {
        int s0 = csr16[i];
        short8 v0 = *(const short8*)(H + (size_t)s0 * F + c);
#pragma unroll
        for (int j = 0; j < 8; ++j) acc[j] += bf2f((ushort)v0[j]);
    }

#pragma unroll
    for (int j = 0; j < 8; ++j) acc[j] += __shfl_xor(acc[j], 32);

    if (slot == 0) {
        const short8 h = *(const short8*)(H + (size_t)n * F + c);
        const float4 b0 = *(const float4*)(bias + c);
        const float4 b1 = *(const float4*)(bias + c + 4);
        float bb[8] = {b0.x, b0.y, b0.z, b0.w, b1.x, b1.y, b1.z, b1.w};
        float di = dinv[n];
        float s[8];
#pragma unroll
        for (int j = 0; j < 8; ++j)
            s[j] = bb[j] + di * (acc[j] + bf2f((ushort)h[j]));

        short8 ov;
        if (MODE == 1) {
#pragma unroll
            for (int j = 0; j < 8; ++j)
                ov[j] = (short)f2bf(fmaxf(s[j], 0.f));
        } else {
            const short8 hv = *(const short8*)(hc + (size_t)n * F + c);
#pragma unroll
            for (int j = 0; j < 8; ++j)
                ov[j] = (short)f2bf(fmaxf(fmaxf(s[j], 0.f) + bf2f((ushort)hv[j]), 0.f));
        }
        *(short8*)(OUT + (size_t)n * F + c) = ov;
    }
}

// ---------------- layer 4: GEMM 256 -> 16, dinv-prescaled bf16 out ----------------

__global__ __launch_bounds__(256) void k_gemm16(const ushort* __restrict__ A,
                                                const float* __restrict__ W4,
                                                const float* __restrict__ dinv,
                                                ushort* __restrict__ C) {
    __shared__ float Ws[256][16];
    const int t = threadIdx.x;
    {
        const float4* wp = (const float4*)(W4 + (size_t)t * 16);
        float4 a = wp[0], b = wp[1], c = wp[2], d = wp[3];
        float4* sp = (float4*)&Ws[t][0];
        sp[0] = a; sp[1] = b; sp[2] = c; sp[3] = d;
    }
    __syncthreads();
    int row = blockIdx.x * 256 + t;
    if (row >= N_NODES) return;
    const short8* ap = (const short8*)(A + (size_t)row * F);
    float acc[16];
#pragma unroll
    for (int c = 0; c < 16; ++c) acc[c] = 0.f;
    for (int k8 = 0; k8 < 32; ++k8) {
        short8 a8 = ap[k8];
#pragma unroll
        for (int j = 0; j < 8; ++j) {
            float av = bf2f((ushort)a8[j]);
            const float4* wr = (const float4*)&Ws[k8 * 8 + j][0];
            float4 w0 = wr[0], w1 = wr[1], w2 = wr[2], w3 = wr[3];
            acc[0]  += av * w0.x; acc[1]  += av * w0.y;
            acc[2]  += av * w0.z; acc[3]  += av * w0.w;
            acc[4]  += av * w1.x; acc[5]  += av * w1.y;
            acc[6]  += av * w1.z; acc[7]  += av * w1.w;
            acc[8]  += av * w2.x; acc[9]  += av * w2.y;
            acc[10] += av * w2.z; acc[11] += av * w2.w;
            acc[12] += av * w3.x; acc[13] += av * w3.y;
            acc[14] += av * w3.z; acc[15] += av * w3.w;
        }
    }
    float dv = dinv[row];
    short8 o0, o1;
#pragma unroll
    for (int c = 0; c < 8; ++c) o0[c] = (short)f2bf(acc[c] * dv);
#pragma unroll
    for (int c = 0; c < 8; ++c) o1[c] = (short)f2bf(acc[8 + c] * dv);
    short8* op = (short8*)(C + (size_t)row * 16);
    op[0] = o0; op[1] = o1;
}

// ---------------- fused layer-4 gather + mean-pool accumulate ----------------

__global__ __launch_bounds__(256) void k_g16pool(const ushort* __restrict__ G16,
                                                 const float* __restrict__ bias,
                                                 const float* __restrict__ dinv,
                                                 const int* __restrict__ rowptr,
                                                 const ushort* __restrict__ csr16,
                                                 const int* __restrict__ batch,
                                                 float* __restrict__ pool,
                                                 float* __restrict__ cnt) {
    __shared__ float ps[NGRAPH][NCLS];
    __shared__ float pc[NGRAPH];
    for (int i = threadIdx.x; i < NGRAPH * NCLS; i += 256) ((float*)ps)[i] = 0.f;
    if (threadIdx.x < NGRAPH) pc[threadIdx.x] = 0.f;
    __syncthreads();

    int gid = blockIdx.x * 256 + threadIdx.x;
    int n = gid >> 2;
    int q = (gid & 3) * 4;
    if (n < N_NODES) {
        float ax = 0.f, ay = 0.f, az = 0.f, aw = 0.f;
        const int end = rowptr[n + 1];
        for (int i = rowptr[n]; i < end; ++i) {
            int s0 = csr16[i];
            const uint2 u = *(const uint2*)(G16 + (size_t)s0 * 16 + q);
            ax += bflo(u.x); ay += bfhi(u.x);
            az += bflo(u.y); aw += bfhi(u.y);
        }
        const uint2 hu = *(const uint2*)(G16 + (size_t)n * 16 + q);
        const float4 b = *(const float4*)(bias + q);
        float di = dinv[n];
        int g = batch[n];
        atomicAdd(&ps[g][q + 0], b.x + di * (ax + bflo(hu.x)));
        atomicAdd(&ps[g][q + 1], b.y + di * (ay + bfhi(hu.x)));
        atomicAdd(&ps[g][q + 2], b.z + di * (az + bflo(hu.y)));
        atomicAdd(&ps[g][q + 3], b.w + di * (aw + bfhi(hu.y)));
        if ((gid & 3) == 0) atomicAdd(&pc[g], 1.f);
    }
    __syncthreads();

    for (int i = threadIdx.x; i < NGRAPH * NCLS; i += 256) {
        float v = ((float*)ps)[i];
        if (v != 0.f) unsafeAtomicAdd(&pool[i], v);
    }
    if (threadIdx.x < NGRAPH) {
        float v = pc[threadIdx.x];
        if (v > 0.f) unsafeAtomicAdd(&cnt[threadIdx.x], v);
    }
}

__global__ __launch_bounds__(256) void k_final(const float* __restrict__ pool,
                                               const float* __restrict__ cnt,
                                               float* __restrict__ out) {
    int i = blockIdx.x * 256 + threadIdx.x;
    if (i < NGRAPH * NCLS) out[i] = pool[i] / fmaxf(cnt[i >> 4], 1.f);
}

// ---------------- host ----------------

extern "C" void kernel_launch(void* const* d_in, const int* in_sizes, int n_in,
                              void* d_out, int out_size, void* d_ws, size_t ws_size,
                              hipStream_t stream) {
    const float* x   = (const float*)d_in[0];
    const int*   ei  = (const int*)d_in[1];
    const int*   bvec= (const int*)d_in[2];
    const float* W1  = (const float*)d_in[3];
    const float* b1  = (const float*)d_in[4];
    const float* W2  = (const float*)d_in[5];
    const float* b2  = (const float*)d_in[6];
    const float* W3  = (const float*)d_in[7];
    const float* b3  = (const float*)d_in[8];
    const float* W4  = (const float*)d_in[9];
    const float* b4  = (const float*)d_in[10];
    float* out = (float*)d_out;

    const int* src = ei;
    const int* dst = ei + N_EDGES;

    const size_t NF = (size_t)N_NODES * F;            // 12.8M elems
    ushort* P   = (ushort*)d_ws;                       // NF bf16
    ushort* Q   = P + NF;                              // NF bf16
    ushort* Hg  = Q + NF;                              // NF bf16 (prescaled GEMM out)
    ushort* G16 = Hg + NF;                             // N*16 bf16 (prescaled)
    float*  aux = (float*)(G16 + (size_t)N_NODES * 16 + 64);
    int*    ecnt   = (int*)aux;                        // N
    float*  dinv   = aux + N_NODES;                    // N
    int*    rowptr = (int*)(aux + 2 * N_NODES);        // N+1 (+pad)
    int*    cursor = (int*)(aux + 3 * N_NODES + 64);   // N
    int*    blkSum = (int*)(aux + 4 * N_NODES + 64);   // 256
    ushort* csr16  = (ushort*)(blkSum + 256);          // E ushorts
    float*  pool   = (float*)(csr16 + N_EDGES);        // 1024
    float*  cnt    = pool + NGRAPH * NCLS;             // 64
    ushort* Wp     = (ushort*)(cnt + NGRAPH);          // 3 x 65536

    const int BN = NBLK_N;                        // 196
    const int BE = (N_EDGES + 255) / 256;         // 3125
    const int BM = (N_NODES + 31) / 32;           // 1563 MFMA blocks (BM=32)
    const int BG = (N_NODES * 64 + 255) / 256;    // 12500 (wave/node)
    const int B4 = (N_NODES * 4 + 255) / 256;     // 782

    // ---- CSR build + dinv + zero-init
    k_init<<<BN, 256, 0, stream>>>(ecnt, pool, cnt);
    k_count<<<BE, 256, 0, stream>>>(dst, ecnt);
    k_scan_block<<<BN, 256, 0, stream>>>(ecnt, rowptr, blkSum, dinv);
    k_scan_add<<<BN, 256, 0, stream>>>(blkSum, rowptr, cursor);
    k_fill_csr<<<BE, 256, 0, stream>>>(src, dst, cursor, csr16);

    // ---- weight packs (single launch)
    k_wpack3<<<96, 256, 0, stream>>>(W1, W2, W3, Wp);

    // ---- layer 1 (cast fused into GEMM): Hg = dinv*(x@W1); P = relu(agg(Hg))
    k_mfma256<1><<<BM, 256, 0, stream>>>(x, Wp, dinv, Hg);
    k_gather256<1><<<BG, 256, 0, stream>>>(Hg, b1, dinv, rowptr, csr16, nullptr, P);

    // ---- layer 2: Hg = dinv*(P@W2); Q = relu(relu(agg(Hg)) + P)
    k_mfma256<0><<<BM, 256, 0, stream>>>(P, Wp + 65536, dinv, Hg);
    k_gather256<2><<<BG, 256, 0, stream>>>(Hg, b2, dinv, rowptr, csr16, P, Q);

    // ---- layer 3: Hg = dinv*(Q@W3); P = relu(relu(agg(Hg)) + Q)
    k_mfma256<0><<<BM, 256, 0, stream>>>(Q, Wp + 131072, dinv, Hg);
    k_gather256<2><<<BG, 256, 0, stream>>>(Hg, b3, dinv, rowptr, csr16, Q, P);

    // ---- layer 4: G16 = dinv*(P@W4); fused gather+pool
    k_gemm16<<<BN, 256, 0, stream>>>(P, W4, dinv, G16);
    k_g16pool<<<B4, 256, 0, stream>>>(G16, b4, dinv, rowptr, csr16, bvec, pool, cnt);

    // ---- finalize
    k_final<<<4, 256, 0, stream>>>(pool, cnt, out);
}